// Round 1
// baseline (504.646 us; speedup 1.0000x reference)
//
#include <hip/hip_runtime.h>
#include <math.h>

// Shapes fixed by reference setup_inputs()
constexpr int B  = 8;
constexpr int H  = 16;
constexpr int NT = 512;
constexpr int NV = 576;
constexpr int TILE = 64;
constexpr float INV_H2 = 1.0f / (float)(H * H);

// ws layout: text_acc[2][B][NT] then vis_acc[2][B][NV]
constexpr int TEXT_N = 2 * B * NT;  // 8192
constexpr int VIS_N  = 2 * B * NV;  // 9216

__global__ void zero_ws_kernel(float* __restrict__ ws, int n) {
    int i = blockIdx.x * blockDim.x + threadIdx.x;
    if (i < n) ws[i] = 0.0f;
}

// One block per (k-tile, i-tile, b+B*layer). 256 threads.
// Computes H-mean of t and v tiles (registers), transposes v via LDS,
// forms Q = t_mean * v_mean^T elementwise, reduces rows (-> text_diag)
// and cols (-> vision_diag), atomically accumulates to global ws.
__global__ __launch_bounds__(256) void fused_diag_kernel(
    const float* __restrict__ t0, const float* __restrict__ v0,
    const float* __restrict__ t1, const float* __restrict__ v1,
    float* __restrict__ text_acc,   // [2][B][NT]
    float* __restrict__ vis_acc)    // [2][B][NV]
{
    const int ktile = blockIdx.x;   // 0..NV/TILE-1
    const int itile = blockIdx.y;   // 0..NT/TILE-1
    const int bz    = blockIdx.z;   // 0..2*B-1
    const int b     = bz & (B - 1);
    const int layer = bz >> 3;

    const float* __restrict__ T = layer ? t1 : t0;  // [B][H][NT][NV]
    const float* __restrict__ V = layer ? v1 : v0;  // [B][H][NV][NT]

    const int tid = threadIdx.x;
    const int c = tid & 15;   // column group: floats 4c..4c+3
    const int g = tid >> 4;   // row group: rows g, g+16, g+32, g+48

    const int i0 = itile * TILE;
    const int k0 = ktile * TILE;

    const size_t tbase = (size_t)b * H * NT * NV + (size_t)i0 * NV + k0;
    const size_t vbase = (size_t)b * H * NV * NT + (size_t)k0 * NT + i0;

    float4 tacc[4];
    float4 vacc[4];
#pragma unroll
    for (int r = 0; r < 4; ++r) {
        tacc[r] = make_float4(0.f, 0.f, 0.f, 0.f);
        vacc[r] = make_float4(0.f, 0.f, 0.f, 0.f);
    }

    for (int h = 0; h < H; ++h) {
        const float* tp = T + tbase + (size_t)h * NT * NV;
        const float* vp = V + vbase + (size_t)h * NV * NT;
#pragma unroll
        for (int r = 0; r < 4; ++r) {
            const int row = g + 16 * r;
            const float4 tv = *(const float4*)(tp + (size_t)row * NV + 4 * c);
            const float4 vv = *(const float4*)(vp + (size_t)row * NT + 4 * c);
            tacc[r].x += tv.x; tacc[r].y += tv.y; tacc[r].z += tv.z; tacc[r].w += tv.w;
            vacc[r].x += vv.x; vacc[r].y += vv.y; vacc[r].z += vv.z; vacc[r].w += vv.w;
        }
    }

    // LDS: v tile transposed access. Pad row stride to 65 -> 2-way bank alias (free).
    __shared__ float vlds[TILE * 65];
    __shared__ float rowsum[TILE];
    __shared__ float colsum[TILE];

    if (tid < TILE) {
        rowsum[tid] = 0.0f;
        colsum[tid] = 0.0f;
    }

#pragma unroll
    for (int r = 0; r < 4; ++r) {
        const int kk = g + 16 * r;          // v row index (NV dim within tile)
        float* p = &vlds[kk * 65 + 4 * c];  // cols ii = 4c..4c+3 (NT dim)
        p[0] = vacc[r].x; p[1] = vacc[r].y; p[2] = vacc[r].z; p[3] = vacc[r].w;
    }
    __syncthreads();

    // Q[ii][kk] = t_sum[ii][kk] * v_sum[kk][ii]; thread's t element:
    // ii = g+16r, kk = 4c+j.
    float colpart[4] = {0.f, 0.f, 0.f, 0.f};
#pragma unroll
    for (int r = 0; r < 4; ++r) {
        const int ii = g + 16 * r;
        const float tq[4] = {tacc[r].x, tacc[r].y, tacc[r].z, tacc[r].w};
        float rp = 0.f;
#pragma unroll
        for (int j = 0; j < 4; ++j) {
            const int kk = 4 * c + j;
            const float q = tq[j] * vlds[kk * 65 + ii];
            rp += q;
            colpart[j] += q;
        }
        atomicAdd(&rowsum[ii], rp);
    }
#pragma unroll
    for (int j = 0; j < 4; ++j) {
        atomicAdd(&colsum[4 * c + j], colpart[j]);
    }
    __syncthreads();

    const int lb = layer * B + b;
    if (tid < TILE) {
        atomicAdd(&text_acc[(size_t)lb * NT + i0 + tid], rowsum[tid] * INV_H2);
    } else if (tid < 2 * TILE) {
        const int kk = tid - TILE;
        atomicAdd(&vis_acc[(size_t)lb * NV + k0 + kk], colsum[kk] * INV_H2);
    }
}

// Single block: weighted sum of -log(clip(x)) over all diag entries.
// total = sum_layers 0.5*(mean_text + mean_vis) / 2
//       = sum_text_entries (-log clip)*0.25/(B*NT) + sum_vis_entries (-log clip)*0.25/(B*NV)
__global__ __launch_bounds__(256) void finalize_kernel(
    const float* __restrict__ text_acc,
    const float* __restrict__ vis_acc,
    float* __restrict__ out)
{
    const int tid = threadIdx.x;
    const float wt = 0.25f / (float)(B * NT);
    const float wv = 0.25f / (float)(B * NV);

    float s = 0.f;
    for (int i = tid; i < TEXT_N; i += 256) {
        float x = text_acc[i];
        x = fminf(fmaxf(x, 1e-8f), 1.0f);
        s += -logf(x) * wt;
    }
    for (int i = tid; i < VIS_N; i += 256) {
        float x = vis_acc[i];
        x = fminf(fmaxf(x, 1e-8f), 1.0f);
        s += -logf(x) * wv;
    }

    // wave64 reduce
#pragma unroll
    for (int off = 32; off > 0; off >>= 1) s += __shfl_down(s, off, 64);

    __shared__ float wsum[4];
    if ((tid & 63) == 0) wsum[tid >> 6] = s;
    __syncthreads();
    if (tid == 0) out[0] = wsum[0] + wsum[1] + wsum[2] + wsum[3];
}

extern "C" void kernel_launch(void* const* d_in, const int* in_sizes, int n_in,
                              void* d_out, int out_size, void* d_ws, size_t ws_size,
                              hipStream_t stream) {
    const float* t0 = (const float*)d_in[0];
    const float* v0 = (const float*)d_in[1];
    const float* t1 = (const float*)d_in[2];
    const float* v1 = (const float*)d_in[3];

    float* text_acc = (float*)d_ws;
    float* vis_acc  = text_acc + TEXT_N;
    float* out      = (float*)d_out;

    // 1. zero accumulators (d_ws is poisoned to 0xAA before every launch)
    {
        const int n = TEXT_N + VIS_N;
        zero_ws_kernel<<<(n + 255) / 256, 256, 0, stream>>>(text_acc, n);
    }

    // 2. fused mean + diag products + row/col reduction
    {
        dim3 grid(NV / TILE, NT / TILE, 2 * B);  // (9, 8, 16)
        fused_diag_kernel<<<grid, 256, 0, stream>>>(t0, v0, t1, v1, text_acc, vis_acc);
    }

    // 3. clip/log/mean -> scalar
    finalize_kernel<<<1, 256, 0, stream>>>(text_acc, vis_acc, out);
}